// Round 1
// baseline (1651.550 us; speedup 1.0000x reference)
//
#include <hip/hip_runtime.h>
#include <math.h>

// Problem constants
#define B_   64
#define T_   64
#define E_   512
#define DM   1024   // d_model
#define DI   2048   // d_inner
#define DS   16     // d_state
#define DTR  64     // dt_rank
#define M_   4096   // B*T rows

// ---------------------------------------------------------------------------
// Generic fp32 GEMM: C[M x N] = act(A[M x K] @ B[K x N] + bias)
// 128x128 tile, BK=16, 256 threads, 8x8 micro-tile per thread.
// A is given as two pointers with a K split point so G1 can fuse the
// concat([spatial, temporal]) without materializing x.
// ACT: 0 = none, 1 = relu, 2 = softplus
// ---------------------------------------------------------------------------
template<int ACT>
__global__ __launch_bounds__(256) void gemm128(
    const float* __restrict__ A1, int lda1,
    const float* __restrict__ A2, int lda2, int Ksplit,
    const float* __restrict__ Bm, int ldb,
    float* __restrict__ C, int ldc,
    const float* __restrict__ bias,
    int Ndim, int Kdim)
{
    __shared__ float As[16][132];   // [k][m], +4 pad keeps float4 alignment
    __shared__ float Bs[16][132];   // [k][n]
    const int tid = threadIdx.x;
    const int bm = blockIdx.y * 128;
    const int bn = blockIdx.x * 128;
    const int tm = (tid >> 4) * 8;
    const int tn = (tid & 15) * 8;
    float acc[8][8] = {};

    for (int k0 = 0; k0 < Kdim; k0 += 16) {
        // ---- load A tile (128 rows x 16 k), transpose into As[k][m]
        #pragma unroll
        for (int it = 0; it < 2; ++it) {
            int i = tid + it * 256;         // over 512 float4s
            int r = i >> 2;                 // row in tile 0..127
            int c = (i & 3) * 4;            // k offset 0,4,8,12
            int gk = k0 + c;
            const float* ap = (gk < Ksplit)
                ? (A1 + (size_t)(bm + r) * lda1 + gk)
                : (A2 + (size_t)(bm + r) * lda2 + (gk - Ksplit));
            float4 v = *(const float4*)ap;
            As[c + 0][r] = v.x; As[c + 1][r] = v.y;
            As[c + 2][r] = v.z; As[c + 3][r] = v.w;
        }
        // ---- load B tile (16 k x 128 n) directly
        #pragma unroll
        for (int it = 0; it < 2; ++it) {
            int i = tid + it * 256;
            int k = i >> 5;                 // 0..15
            int n = (i & 31) * 4;           // 0..124
            int gn = bn + n;
            float4 v = make_float4(0.f, 0.f, 0.f, 0.f);
            if (gn < Ndim) v = *(const float4*)(Bm + (size_t)(k0 + k) * ldb + gn);
            *(float4*)&Bs[k][n] = v;
        }
        __syncthreads();
        #pragma unroll
        for (int k = 0; k < 16; ++k) {
            float a[8], b[8];
            *(float4*)&a[0] = *(const float4*)&As[k][tm];
            *(float4*)&a[4] = *(const float4*)&As[k][tm + 4];
            *(float4*)&b[0] = *(const float4*)&Bs[k][tn];
            *(float4*)&b[4] = *(const float4*)&Bs[k][tn + 4];
            #pragma unroll
            for (int i = 0; i < 8; ++i)
                #pragma unroll
                for (int j = 0; j < 8; ++j)
                    acc[i][j] = fmaf(a[i], b[j], acc[i][j]);
        }
        __syncthreads();
    }
    #pragma unroll
    for (int i = 0; i < 8; ++i) {
        int gm = bm + tm + i;
        #pragma unroll
        for (int j = 0; j < 8; ++j) {
            int gn = bn + tn + j;
            if (gn < Ndim) {
                float v = acc[i][j];
                if (bias) v += bias[gn];
                if (ACT == 1) v = fmaxf(v, 0.f);
                if (ACT == 2) v = (v > 20.f) ? v : log1pf(expf(v));
                C[(size_t)gm * ldc + gn] = v;
            }
        }
    }
}

// ---------------------------------------------------------------------------
// Causal depthwise conv (K=4) + bias + silu.  xi = xz[:, :, 0:2048]
// xc[b,t,d] = silu( sum_k xi[b, t+k-3, d] * conv_w[d,k] + conv_b[d] )
// ---------------------------------------------------------------------------
__global__ __launch_bounds__(256) void conv_silu_kernel(
    const float* __restrict__ xz, const float* __restrict__ conv_w,
    const float* __restrict__ conv_b, float* __restrict__ xc)
{
    int idx = blockIdx.x * 256 + threadIdx.x;   // over M_*DI
    int d = idx & (DI - 1);
    int bt = idx >> 11;                          // DI = 2048 = 2^11
    int t = bt & (T_ - 1);
    float acc = conv_b[d];
    #pragma unroll
    for (int k = 0; k < 4; ++k) {
        int tt = t + k - 3;
        if (tt >= 0)
            acc = fmaf(xz[(size_t)(bt + (tt - t)) * 4096 + d], conv_w[d * 4 + k], acc);
    }
    xc[idx] = acc / (1.f + expf(-acc));          // silu
}

// ---------------------------------------------------------------------------
// Selective scan. One thread per (b, d); h[16] in registers; sequential t.
// Reads dt from dtY and writes gated y back in-place (safe: same (b,t,d)
// location, read-then-write within the iteration).
// Fuses: + xc*D_skip, * silu(z).
// ---------------------------------------------------------------------------
__global__ __launch_bounds__(256) void scan_kernel(
    const float* __restrict__ proj,   // (M_, 96): [64:80)=Bs, [80:96)=Cs
    float* __restrict__ dtY,          // (M_, DI) in: softplus dt, out: gated y
    const float* __restrict__ xc,     // (M_, DI)
    const float* __restrict__ xz,     // (M_, 4096), z = cols [2048, 4096)
    const float* __restrict__ A_log,  // (DI, 16)
    const float* __restrict__ D_skip) // (DI)
{
    int d = blockIdx.x * 256 + threadIdx.x;  // 0..2047
    int b = blockIdx.y;                      // 0..63
    float A[16];
    #pragma unroll
    for (int n = 0; n < 16; ++n) A[n] = -expf(A_log[d * 16 + n]);
    float Dv = D_skip[d];
    float h[16];
    #pragma unroll
    for (int n = 0; n < 16; ++n) h[n] = 0.f;

    for (int t = 0; t < T_; ++t) {
        int row = b * T_ + t;
        size_t off = (size_t)row * DI + d;
        float dt = dtY[off];
        float xv = xc[off];
        float dtx = dt * xv;
        const float* Brow = proj + (size_t)row * 96 + 64;
        const float* Crow = proj + (size_t)row * 96 + 80;
        float y = 0.f;
        #pragma unroll
        for (int n = 0; n < 16; ++n) {
            float dA = expf(dt * A[n]);
            h[n] = fmaf(dA, h[n], dtx * Brow[n]);
            y = fmaf(h[n], Crow[n], y);
        }
        float sk = fmaf(xv, Dv, y);
        float z = xz[(size_t)row * 4096 + 2048 + d];
        float g = z / (1.f + expf(-z));          // silu(z)
        dtY[off] = sk * g;
    }
}

// ---------------------------------------------------------------------------
// Head: out[row, 0:6] = h2[row, :] @ W3 + b3.  One wave per row.
// ---------------------------------------------------------------------------
__global__ __launch_bounds__(256) void head_kernel(
    const float* __restrict__ h2, const float* __restrict__ W3,
    const float* __restrict__ b3, float* __restrict__ out)
{
    int row = blockIdx.x * 4 + (threadIdx.x >> 6);
    int lane = threadIdx.x & 63;
    const float* hr = h2 + (size_t)row * 256;
    float acc[6] = {0.f, 0.f, 0.f, 0.f, 0.f, 0.f};
    #pragma unroll
    for (int kk = 0; kk < 4; ++kk) {
        int k = lane + kk * 64;
        float hv = hr[k];
        #pragma unroll
        for (int n = 0; n < 6; ++n) acc[n] = fmaf(hv, W3[k * 6 + n], acc[n]);
    }
    #pragma unroll
    for (int n = 0; n < 6; ++n) {
        float v = acc[n];
        #pragma unroll
        for (int off = 32; off > 0; off >>= 1) v += __shfl_down(v, off);
        if (lane == 0) out[(size_t)row * 6 + n] = v + b3[n];
    }
}

// ---------------------------------------------------------------------------
extern "C" void kernel_launch(void* const* d_in, const int* in_sizes, int n_in,
                              void* d_out, int out_size, void* d_ws, size_t ws_size,
                              hipStream_t stream)
{
    const float* spatial  = (const float*)d_in[0];
    const float* temporal = (const float*)d_in[1];
    const float* W_in     = (const float*)d_in[2];
    const float* conv_w   = (const float*)d_in[3];
    const float* conv_b   = (const float*)d_in[4];
    const float* W_x      = (const float*)d_in[5];
    const float* W_dt     = (const float*)d_in[6];
    const float* b_dt     = (const float*)d_in[7];
    const float* A_log    = (const float*)d_in[8];
    const float* D_skip   = (const float*)d_in[9];
    const float* W_out    = (const float*)d_in[10];
    const float* W1       = (const float*)d_in[11];
    const float* b1       = (const float*)d_in[12];
    const float* W2       = (const float*)d_in[13];
    const float* b2       = (const float*)d_in[14];
    const float* W3       = (const float*)d_in[15];
    const float* b3       = (const float*)d_in[16];
    float* out = (float*)d_out;

    // Workspace layout (floats). Peak ~136 MB.
    float* ws   = (float*)d_ws;
    float* xz   = ws;                      // (M_, 4096)  64 MB
    float* xc   = ws + 16777216;           // (M_, 2048)  32 MB
    float* dtY  = ws + 25165824;           // (M_, 2048)  32 MB (dt, then y)
    float* proj = ws + 33554432;           // (M_, 96)    1.5 MB
    // After scan, xz/xc are dead; reuse the front region:
    float* f    = ws;                      // (M_, 1024)  16 MB
    float* h1   = ws + 4194304;            // (M_, 512)    8 MB
    float* h2   = ws + 6291456;            // (M_, 256)    4 MB

    dim3 blk(256);
    const int BIG = 1 << 30;

    // G1: xz = concat(spatial, temporal) @ W_in   (4096 x 4096, K=1024)
    gemm128<0><<<dim3(32, 32), blk, 0, stream>>>(
        spatial, E_, temporal, E_, E_, W_in, 4096, xz, 4096, nullptr, 4096, 1024);

    // conv + silu -> xc
    conv_silu_kernel<<<dim3(32768), blk, 0, stream>>>(xz, conv_w, conv_b, xc);

    // G2: proj = xc @ W_x   (4096 x 96, K=2048)
    gemm128<0><<<dim3(1, 32), blk, 0, stream>>>(
        xc, DI, xc, DI, BIG, W_x, 96, proj, 96, nullptr, 96, DI);

    // G3: dt = softplus(proj[:, :64] @ W_dt + b_dt)   (4096 x 2048, K=64)
    gemm128<2><<<dim3(16, 32), blk, 0, stream>>>(
        proj, 96, proj, 96, BIG, W_dt, DI, dtY, DI, b_dt, DI, DTR);

    // Selective scan + skip + gating -> dtY becomes y
    scan_kernel<<<dim3(8, 64), blk, 0, stream>>>(proj, dtY, xc, xz, A_log, D_skip);

    // G4: f = y @ W_out   (4096 x 1024, K=2048)
    gemm128<0><<<dim3(8, 32), blk, 0, stream>>>(
        dtY, DI, dtY, DI, BIG, W_out, DM, f, DM, nullptr, DM, DI);

    // G5: h1 = relu(f @ W1 + b1)   (4096 x 512, K=1024)
    gemm128<1><<<dim3(4, 32), blk, 0, stream>>>(
        f, DM, f, DM, BIG, W1, 512, h1, 512, b1, 512, DM);

    // G6: h2 = relu(h1 @ W2 + b2)   (4096 x 256, K=512)
    gemm128<1><<<dim3(2, 32), blk, 0, stream>>>(
        h1, 512, h1, 512, BIG, W2, 256, h2, 256, b2, 256, 512);

    // G7: out = h2 @ W3 + b3   (4096 x 6, K=256)
    head_kernel<<<dim3(1024), blk, 0, stream>>>(h2, W3, b3, out);
}

// Round 2
// 490.895 us; speedup vs baseline: 3.3644x; 3.3644x over previous
//
#include <hip/hip_runtime.h>
#include <hip/hip_bf16.h>
#include <math.h>

// Problem constants
#define B_   64
#define T_   64
#define E_   512
#define DM   1024   // d_model
#define DI   2048   // d_inner
#define DS   16     // d_state
#define DTR  64     // dt_rank
#define M_   4096   // B*T rows

typedef __hip_bfloat16 bf16;
typedef __attribute__((ext_vector_type(8))) short bf16x8;   // 8 bf16 = 4 VGPRs
typedef __attribute__((ext_vector_type(4))) float f32x4;

// ---------------------------------------------------------------------------
// bf16 MFMA GEMM (m97 structure): C[M x N] = act(A @ B + bias)
//   A  : bf16 (M x K) row-major, lda
//   Bt : bf16 (N x K) row-major (i.e. B transposed), ldb
//   C  : fp32 or bf16 per OUTBF
// 128x128 tile, BK=32, 256 threads (4 waves, 2x2 wave grid, 4x4 MFMA tiles of
// 16x16x32 per wave). Staging via global_load_lds width=16 (wave-uniform LDS
// base + lane*16 — LDS layout is linear row-major [row][k], no padding).
// ACT: 0 none, 1 relu, 2 softplus
// ---------------------------------------------------------------------------
template<int ACT, int OUTBF>
__global__ __launch_bounds__(256) void gemm_mfma(
    const bf16* __restrict__ A, int lda,
    const bf16* __restrict__ Bt, int ldb,
    void* __restrict__ Cv, int ldc,
    const float* __restrict__ bias,
    int Ndim, int Kdim)
{
    __shared__ __align__(16) bf16 As[128 * 32];
    __shared__ __align__(16) bf16 Bs[128 * 32];
    const int tid  = threadIdx.x;
    const int wave = tid >> 6;
    const int lane = tid & 63;
    const int bm = blockIdx.y * 128;
    const int bn = blockIdx.x * 128;
    // staging: per issue, 64 lanes cover 16 rows x 4 k-chunks of 8 bf16 (16 B)
    const int lrow = lane >> 2;         // 0..15
    const int lkc  = (lane & 3) * 8;    // k element offset 0,8,16,24
    const int arow0 = wave * 32;        // this wave stages rows [arow0, arow0+32)
    // compute: wave (2x2) x 4x4 tiles of 16x16
    const int wm = (wave >> 1) * 64;
    const int wn = (wave & 1) * 64;
    const int fm = lane & 15;           // fragment row/col
    const int fq = lane >> 4;           // quad 0..3

    f32x4 acc[4][4];
    #pragma unroll
    for (int i = 0; i < 4; ++i)
        #pragma unroll
        for (int j = 0; j < 4; ++j)
            acc[i][j] = (f32x4){0.f, 0.f, 0.f, 0.f};

    for (int k0 = 0; k0 < Kdim; k0 += 32) {
        #pragma unroll
        for (int j = 0; j < 2; ++j) {
            // A tile rows
            int row = arow0 + j * 16 + lrow;
            const bf16* ga = A + (size_t)(bm + row) * lda + k0 + lkc;
            __builtin_amdgcn_global_load_lds(
                (const __attribute__((address_space(1))) void*)ga,
                (__attribute__((address_space(3))) void*)&As[(arow0 + j * 16) * 32],
                16, 0, 0);
            // B tile rows (clamp OOB n-rows to a valid row; cols >= Ndim are
            // never stored, and MFMA output columns are independent)
            int brow = bn + arow0 + j * 16 + lrow;
            if (brow >= Ndim) brow = Ndim - 1;
            const bf16* gb = Bt + (size_t)brow * ldb + k0 + lkc;
            __builtin_amdgcn_global_load_lds(
                (const __attribute__((address_space(1))) void*)gb,
                (__attribute__((address_space(3))) void*)&Bs[(arow0 + j * 16) * 32],
                16, 0, 0);
        }
        __syncthreads();
        bf16x8 a[4], b[4];
        #pragma unroll
        for (int i = 0; i < 4; ++i)
            a[i] = *(const bf16x8*)&As[(wm + i * 16 + fm) * 32 + fq * 8];
        #pragma unroll
        for (int j = 0; j < 4; ++j)
            b[j] = *(const bf16x8*)&Bs[(wn + j * 16 + fm) * 32 + fq * 8];
        #pragma unroll
        for (int i = 0; i < 4; ++i)
            #pragma unroll
            for (int j = 0; j < 4; ++j)
                acc[i][j] = __builtin_amdgcn_mfma_f32_16x16x32_bf16(
                    a[i], b[j], acc[i][j], 0, 0, 0);
        __syncthreads();
    }

    // Epilogue. C/D layout: col = lane&15, row = (lane>>4)*4 + r
    #pragma unroll
    for (int i = 0; i < 4; ++i) {
        int rowb = bm + wm + i * 16 + fq * 4;
        #pragma unroll
        for (int j = 0; j < 4; ++j) {
            int col = bn + wn + j * 16 + fm;
            if (col < Ndim) {
                float bv = bias ? bias[col] : 0.f;
                #pragma unroll
                for (int r = 0; r < 4; ++r) {
                    float v = acc[i][j][r] + bv;
                    if (ACT == 1) v = fmaxf(v, 0.f);
                    if (ACT == 2) v = (v > 20.f) ? v : log1pf(expf(v));
                    size_t off = (size_t)(rowb + r) * ldc + col;
                    if (OUTBF) ((bf16*)Cv)[off] = __float2bfloat16(v);
                    else       ((float*)Cv)[off] = v;
                }
            }
        }
    }
}

// ---------------------------------------------------------------------------
// fp32 (K x N) -> bf16 transposed (N x K). 32x32 LDS tile. K,N multiples of 32.
// ---------------------------------------------------------------------------
__global__ __launch_bounds__(256) void tconv_kernel(
    const float* __restrict__ W, bf16* __restrict__ Wt, int K, int N)
{
    __shared__ float tile[32][33];
    int bk = blockIdx.y * 32, bn = blockIdx.x * 32;
    int tx = threadIdx.x & 31, ty = threadIdx.x >> 5;  // ty 0..7
    #pragma unroll
    for (int i = 0; i < 32; i += 8)
        tile[ty + i][tx] = W[(size_t)(bk + ty + i) * N + bn + tx];
    __syncthreads();
    #pragma unroll
    for (int i = 0; i < 32; i += 8)
        Wt[(size_t)(bn + ty + i) * K + bk + tx] = __float2bfloat16(tile[tx][ty + i]);
}

// concat(spatial, temporal) -> bf16 (M_, 1024)
__global__ __launch_bounds__(256) void concat_kernel(
    const float* __restrict__ sp, const float* __restrict__ tp,
    bf16* __restrict__ xb)
{
    int idx = blockIdx.x * 256 + threadIdx.x;   // over M_*256 float4 groups
    int row = idx >> 8;
    int c4 = (idx & 255) * 4;
    const float* src = (c4 < 512) ? (sp + (size_t)row * 512 + c4)
                                  : (tp + (size_t)row * 512 + (c4 - 512));
    float4 v = *(const float4*)src;
    bf16* dst = xb + (size_t)row * 1024 + c4;
    dst[0] = __float2bfloat16(v.x); dst[1] = __float2bfloat16(v.y);
    dst[2] = __float2bfloat16(v.z); dst[3] = __float2bfloat16(v.w);
}

// fp32 -> bf16 flat convert
__global__ __launch_bounds__(256) void f2b_kernel(
    const float* __restrict__ src, bf16* __restrict__ dst, int n)
{
    int i = blockIdx.x * 256 + threadIdx.x;
    if (i < n) dst[i] = __float2bfloat16(src[i]);
}

// ---------------------------------------------------------------------------
// Causal depthwise conv (K=4) + bias + silu, bf16 in, fp32 + bf16 out.
// ---------------------------------------------------------------------------
__global__ __launch_bounds__(256) void conv_silu_kernel(
    const bf16* __restrict__ xzb, const float* __restrict__ conv_w,
    const float* __restrict__ conv_b, float* __restrict__ xc,
    bf16* __restrict__ xcb)
{
    int idx = blockIdx.x * 256 + threadIdx.x;   // over M_*DI
    int d = idx & (DI - 1);
    int bt = idx >> 11;
    int t = bt & (T_ - 1);
    float acc = conv_b[d];
    #pragma unroll
    for (int k = 0; k < 4; ++k) {
        int tt = t + k - 3;
        if (tt >= 0)
            acc = fmaf(__bfloat162float(xzb[(size_t)(bt + (k - 3)) * 4096 + d]),
                       conv_w[d * 4 + k], acc);
    }
    float s = acc / (1.f + expf(-acc));          // silu
    xc[idx] = s;
    xcb[idx] = __float2bfloat16(s);
}

// ---------------------------------------------------------------------------
// Selective scan. One thread per (b, d); h[16] in registers; sequential t.
// Fuses + xc*D_skip and * silu(z). Writes y as bf16 (feeds G4 only).
// ---------------------------------------------------------------------------
__global__ __launch_bounds__(256) void scan_kernel(
    const float* __restrict__ proj,   // (M_, 96): [64:80)=Bs, [80:96)=Cs
    const float* __restrict__ dtv,    // (M_, DI) softplus dt
    const float* __restrict__ xc,     // (M_, DI)
    const bf16*  __restrict__ xzb,    // (M_, 4096), z = cols [2048,4096)
    const float* __restrict__ A_log,  // (DI, 16)
    const float* __restrict__ D_skip, // (DI)
    bf16* __restrict__ yb)            // (M_, DI) out
{
    int d = blockIdx.x * 256 + threadIdx.x;  // 0..2047
    int b = blockIdx.y;                      // 0..63
    float A[16];
    #pragma unroll
    for (int n = 0; n < 16; ++n) A[n] = -expf(A_log[d * 16 + n]);
    float Dv = D_skip[d];
    float h[16];
    #pragma unroll
    for (int n = 0; n < 16; ++n) h[n] = 0.f;

    for (int t = 0; t < T_; ++t) {
        int row = b * T_ + t;
        size_t off = (size_t)row * DI + d;
        float dt = dtv[off];
        float xv = xc[off];
        float dtx = dt * xv;
        const float* Brow = proj + (size_t)row * 96 + 64;
        const float* Crow = proj + (size_t)row * 96 + 80;
        float y = 0.f;
        #pragma unroll
        for (int n = 0; n < 16; ++n) {
            float dA = expf(dt * A[n]);
            h[n] = fmaf(dA, h[n], dtx * Brow[n]);
            y = fmaf(h[n], Crow[n], y);
        }
        float sk = fmaf(xv, Dv, y);
        float z = __bfloat162float(xzb[(size_t)row * 4096 + 2048 + d]);
        float g = z / (1.f + expf(-z));          // silu(z)
        yb[off] = __float2bfloat16(sk * g);
    }
}

// ---------------------------------------------------------------------------
// Head: out[row, 0:6] = h2[row, :] @ W3 + b3.  One wave per row. h2 is bf16.
// ---------------------------------------------------------------------------
__global__ __launch_bounds__(256) void head_kernel(
    const bf16* __restrict__ h2, const float* __restrict__ W3,
    const float* __restrict__ b3, float* __restrict__ out)
{
    int row = blockIdx.x * 4 + (threadIdx.x >> 6);
    int lane = threadIdx.x & 63;
    const bf16* hr = h2 + (size_t)row * 256;
    float acc[6] = {0.f, 0.f, 0.f, 0.f, 0.f, 0.f};
    #pragma unroll
    for (int kk = 0; kk < 4; ++kk) {
        int k = lane + kk * 64;
        float hv = __bfloat162float(hr[k]);
        #pragma unroll
        for (int n = 0; n < 6; ++n) acc[n] = fmaf(hv, W3[k * 6 + n], acc[n]);
    }
    #pragma unroll
    for (int n = 0; n < 6; ++n) {
        float v = acc[n];
        #pragma unroll
        for (int off = 32; off > 0; off >>= 1) v += __shfl_down(v, off);
        if (lane == 0) out[(size_t)row * 6 + n] = v + b3[n];
    }
}

// ---------------------------------------------------------------------------
extern "C" void kernel_launch(void* const* d_in, const int* in_sizes, int n_in,
                              void* d_out, int out_size, void* d_ws, size_t ws_size,
                              hipStream_t stream)
{
    const float* spatial  = (const float*)d_in[0];
    const float* temporal = (const float*)d_in[1];
    const float* W_in     = (const float*)d_in[2];
    const float* conv_w   = (const float*)d_in[3];
    const float* conv_b   = (const float*)d_in[4];
    const float* W_x      = (const float*)d_in[5];
    const float* W_dt     = (const float*)d_in[6];
    const float* b_dt     = (const float*)d_in[7];
    const float* A_log    = (const float*)d_in[8];
    const float* D_skip   = (const float*)d_in[9];
    const float* W_out    = (const float*)d_in[10];
    const float* W1       = (const float*)d_in[11];
    const float* b1       = (const float*)d_in[12];
    const float* W2       = (const float*)d_in[13];
    const float* b2       = (const float*)d_in[14];
    const float* W3       = (const float*)d_in[15];
    const float* b3       = (const float*)d_in[16];
    float* out = (float*)d_out;

    // Workspace layout (bytes). Max footprint 135,790,592 B (== round-1's,
    // known to fit). Aliases are safe by stream order; noted inline.
    char* w = (char*)d_ws;
    bf16*  xzb  = (bf16*)(w + 0);           // (M_,4096) bf16, 32 MiB; dead after scan
    bf16*  f    = (bf16*)(w + 0);           // (M_,1024) bf16, aliases xzb
    bf16*  h1   = (bf16*)(w + 8388608);     // (M_, 512) bf16
    bf16*  h2   = (bf16*)(w + 12582912);    // (M_, 256) bf16
    float* xc   = (float*)(w + 33554432);   // (M_,2048) fp32, 32 MiB; dead after scan
    bf16*  WoT  = (bf16*)(w + 33554432);    // (1024,2048) 4 MiB, written after scan
    bf16*  W1T  = (bf16*)(w + 37748736);    // (512,1024) 1 MiB
    bf16*  W2T  = (bf16*)(w + 38797312);    // (256,512) 256 KiB
    float* dtY  = (float*)(w + 67108864);   // (M_,2048) fp32, 32 MiB
    bf16*  WxT  = (bf16*)(w + 67108864);    // (96,2048) 384 KiB; dead before G3 writes dtY
    bf16*  xcb  = (bf16*)(w + 100663296);   // (M_,2048) bf16, 16 MiB; dead after G2
    bf16*  WdT  = (bf16*)(w + 100663296);   // (2048,64) 256 KiB, written after G2
    bf16*  yb   = (bf16*)(w + 100663296);   // (M_,2048) bf16, written by scan (WdT dead)
    bf16*  xb   = (bf16*)(w + 117440512);   // (M_,1024) bf16, 8 MiB; dead after G1
    bf16*  projb= (bf16*)(w + 117440512);   // (M_,96) bf16, aliases xb
    float* proj = (float*)(w + 125829120);  // (M_,96) fp32, 1.5 MiB
    bf16*  WinT = (bf16*)(w + 127401984);   // (4096,1024) 8 MiB; end 135790592

    dim3 blk(256);

    // Input conversions
    concat_kernel<<<dim3(4096), blk, 0, stream>>>(spatial, temporal, xb);
    tconv_kernel<<<dim3(128, 32), blk, 0, stream>>>(W_in, WinT, 1024, 4096);

    // G1: xzb = xb @ W_in   (4096 x 4096, K=1024) -> bf16
    gemm_mfma<0, 1><<<dim3(32, 32), blk, 0, stream>>>(
        xb, 1024, WinT, 1024, xzb, 4096, nullptr, 4096, 1024);

    // conv + silu -> xc (fp32) + xcb (bf16)
    conv_silu_kernel<<<dim3(32768), blk, 0, stream>>>(xzb, conv_w, conv_b, xc, xcb);

    // G2: proj = xc @ W_x   (4096 x 96, K=2048) -> fp32
    tconv_kernel<<<dim3(3, 64), blk, 0, stream>>>(W_x, WxT, 2048, 96);
    gemm_mfma<0, 0><<<dim3(1, 32), blk, 0, stream>>>(
        xcb, 2048, WxT, 2048, proj, 96, nullptr, 96, 2048);

    // G3: dt = softplus(proj[:, :64] @ W_dt + b_dt) -> fp32 dtY
    tconv_kernel<<<dim3(64, 2), blk, 0, stream>>>(W_dt, WdT, 64, 2048);
    f2b_kernel<<<dim3(1536), blk, 0, stream>>>(proj, projb, M_ * 96);
    gemm_mfma<2, 0><<<dim3(16, 32), blk, 0, stream>>>(
        projb, 96, WdT, 64, dtY, 2048, b_dt, 2048, 64);

    // Selective scan + skip + gating -> yb (bf16, overwrites xcb/WdT region)
    scan_kernel<<<dim3(8, 64), blk, 0, stream>>>(
        proj, dtY, xc, xzb, A_log, D_skip, yb);

    // Late weight transposes into now-dead xc region
    tconv_kernel<<<dim3(32, 64), blk, 0, stream>>>(W_out, WoT, 2048, 1024);
    tconv_kernel<<<dim3(16, 32), blk, 0, stream>>>(W1, W1T, 1024, 512);
    tconv_kernel<<<dim3(8, 16), blk, 0, stream>>>(W2, W2T, 512, 256);

    // G4: f = y @ W_out   (4096 x 1024, K=2048) -> bf16 (over dead xzb)
    gemm_mfma<0, 1><<<dim3(8, 32), blk, 0, stream>>>(
        yb, 2048, WoT, 2048, f, 1024, nullptr, 1024, 2048);

    // G5: h1 = relu(f @ W1 + b1)   (4096 x 512, K=1024)
    gemm_mfma<1, 1><<<dim3(4, 32), blk, 0, stream>>>(
        f, 1024, W1T, 1024, h1, 512, b1, 512, 1024);

    // G6: h2 = relu(h1 @ W2 + b2)   (4096 x 256, K=512)
    gemm_mfma<1, 1><<<dim3(2, 32), blk, 0, stream>>>(
        h1, 512, W2T, 512, h2, 256, b2, 256, 512);

    // G7: out = h2 @ W3 + b3
    head_kernel<<<dim3(1024), blk, 0, stream>>>(h2, W3, b3, out);
}

// Round 3
// 407.235 us; speedup vs baseline: 4.0555x; 1.2054x over previous
//
#include <hip/hip_runtime.h>
#include <hip/hip_bf16.h>
#include <math.h>

// Problem constants
#define B_   64
#define T_   64
#define E_   512
#define DM   1024   // d_model
#define DI   2048   // d_inner
#define DS   16     // d_state
#define DTR  64     // dt_rank
#define M_   4096   // B*T rows

typedef __hip_bfloat16 bf16;
typedef __attribute__((ext_vector_type(8))) short bf16x8;   // 8 bf16 = 4 VGPRs
typedef __attribute__((ext_vector_type(4))) float f32x4;

// ---------------------------------------------------------------------------
// bf16 MFMA GEMM (m97 structure): C[M x N] = act(A @ B + bias)
//   A  : bf16 (M x K) row-major, lda
//   Bt : bf16 (N x K) row-major (i.e. B transposed), ldb
//   C  : fp32 or bf16 per OUTBF
// 128x128 tile, BK=32, 256 threads (4 waves, 2x2 wave grid, 4x4 MFMA tiles of
// 16x16x32 per wave). Staging via global_load_lds width=16.
// ACT: 0 none, 1 relu, 2 softplus.  ATOMIC: split-K over gridDim.z with
// fp32 atomicAdd epilogue (bias must be null, OUTBF must be 0).
// ---------------------------------------------------------------------------
template<int ACT, int OUTBF, int ATOMIC>
__global__ __launch_bounds__(256) void gemm_mfma(
    const bf16* __restrict__ A, int lda,
    const bf16* __restrict__ Bt, int ldb,
    void* __restrict__ Cv, int ldc,
    const float* __restrict__ bias,
    int Ndim, int Kdim)
{
    __shared__ __align__(16) bf16 As[128 * 32];
    __shared__ __align__(16) bf16 Bs[128 * 32];
    const int tid  = threadIdx.x;
    const int wave = tid >> 6;
    const int lane = tid & 63;
    const int bm = blockIdx.y * 128;
    const int bn = blockIdx.x * 128;
    // staging: per issue, 64 lanes cover 16 rows x 4 k-chunks of 8 bf16 (16 B)
    const int lrow = lane >> 2;         // 0..15
    const int lkc  = (lane & 3) * 8;    // k element offset 0,8,16,24
    const int arow0 = wave * 32;        // this wave stages rows [arow0, arow0+32)
    // compute: wave (2x2) x 4x4 tiles of 16x16
    const int wm = (wave >> 1) * 64;
    const int wn = (wave & 1) * 64;
    const int fm = lane & 15;           // fragment row/col
    const int fq = lane >> 4;           // quad 0..3

    int kstart = 0, kend = Kdim;
    if (ATOMIC) {
        int chunk = Kdim / (int)gridDim.z;
        kstart = blockIdx.z * chunk;
        kend = kstart + chunk;
    }

    f32x4 acc[4][4];
    #pragma unroll
    for (int i = 0; i < 4; ++i)
        #pragma unroll
        for (int j = 0; j < 4; ++j)
            acc[i][j] = (f32x4){0.f, 0.f, 0.f, 0.f};

    for (int k0 = kstart; k0 < kend; k0 += 32) {
        #pragma unroll
        for (int j = 0; j < 2; ++j) {
            // A tile rows
            int row = arow0 + j * 16 + lrow;
            const bf16* ga = A + (size_t)(bm + row) * lda + k0 + lkc;
            __builtin_amdgcn_global_load_lds(
                (const __attribute__((address_space(1))) void*)ga,
                (__attribute__((address_space(3))) void*)&As[(arow0 + j * 16) * 32],
                16, 0, 0);
            // B tile rows (clamp OOB n-rows; cols >= Ndim never stored)
            int brow = bn + arow0 + j * 16 + lrow;
            if (brow >= Ndim) brow = Ndim - 1;
            const bf16* gb = Bt + (size_t)brow * ldb + k0 + lkc;
            __builtin_amdgcn_global_load_lds(
                (const __attribute__((address_space(1))) void*)gb,
                (__attribute__((address_space(3))) void*)&Bs[(arow0 + j * 16) * 32],
                16, 0, 0);
        }
        __syncthreads();
        bf16x8 a[4], b[4];
        #pragma unroll
        for (int i = 0; i < 4; ++i)
            a[i] = *(const bf16x8*)&As[(wm + i * 16 + fm) * 32 + fq * 8];
        #pragma unroll
        for (int j = 0; j < 4; ++j)
            b[j] = *(const bf16x8*)&Bs[(wn + j * 16 + fm) * 32 + fq * 8];
        #pragma unroll
        for (int i = 0; i < 4; ++i)
            #pragma unroll
            for (int j = 0; j < 4; ++j)
                acc[i][j] = __builtin_amdgcn_mfma_f32_16x16x32_bf16(
                    a[i], b[j], acc[i][j], 0, 0, 0);
        __syncthreads();
    }

    // Epilogue. C/D layout: col = lane&15, row = (lane>>4)*4 + r
    #pragma unroll
    for (int i = 0; i < 4; ++i) {
        int rowb = bm + wm + i * 16 + fq * 4;
        #pragma unroll
        for (int j = 0; j < 4; ++j) {
            int col = bn + wn + j * 16 + fm;
            if (col < Ndim) {
                float bv = bias ? bias[col] : 0.f;
                #pragma unroll
                for (int r = 0; r < 4; ++r) {
                    float v = acc[i][j][r] + bv;
                    if (ACT == 1) v = fmaxf(v, 0.f);
                    if (ACT == 2) v = (v > 20.f) ? v : __logf(1.f + __expf(v));
                    size_t off = (size_t)(rowb + r) * ldc + col;
                    if (ATOMIC)     atomicAdd(&((float*)Cv)[off], v);
                    else if (OUTBF) ((bf16*)Cv)[off] = __float2bfloat16(v);
                    else            ((float*)Cv)[off] = v;
                }
            }
        }
    }
}

// ---------------------------------------------------------------------------
// fp32 (K x N) -> bf16 transposed (N x K). 32x32 LDS tile. K,N multiples of 32.
// ---------------------------------------------------------------------------
__global__ __launch_bounds__(256) void tconv_kernel(
    const float* __restrict__ W, bf16* __restrict__ Wt, int K, int N)
{
    __shared__ float tile[32][33];
    int bk = blockIdx.y * 32, bn = blockIdx.x * 32;
    int tx = threadIdx.x & 31, ty = threadIdx.x >> 5;  // ty 0..7
    #pragma unroll
    for (int i = 0; i < 32; i += 8)
        tile[ty + i][tx] = W[(size_t)(bk + ty + i) * N + bn + tx];
    __syncthreads();
    #pragma unroll
    for (int i = 0; i < 32; i += 8)
        Wt[(size_t)(bn + ty + i) * K + bk + tx] = __float2bfloat16(tile[tx][ty + i]);
}

// concat(spatial, temporal) -> bf16 (M_, 1024); also zeroes proj (393216 f32,
// needed because G2 accumulates into it with split-K atomics).
__global__ __launch_bounds__(256) void concat_kernel(
    const float* __restrict__ sp, const float* __restrict__ tp,
    bf16* __restrict__ xb, float* __restrict__ proj)
{
    int idx = blockIdx.x * 256 + threadIdx.x;   // over M_*256 float4 groups
    int row = idx >> 8;
    int c4 = (idx & 255) * 4;
    const float* src = (c4 < 512) ? (sp + (size_t)row * 512 + c4)
                                  : (tp + (size_t)row * 512 + (c4 - 512));
    float4 v = *(const float4*)src;
    bf16* dst = xb + (size_t)row * 1024 + c4;
    dst[0] = __float2bfloat16(v.x); dst[1] = __float2bfloat16(v.y);
    dst[2] = __float2bfloat16(v.z); dst[3] = __float2bfloat16(v.w);
    if (idx < 98304)   // 393216 floats / 4
        *(float4*)(proj + (size_t)idx * 4) = make_float4(0.f, 0.f, 0.f, 0.f);
}

// fp32 -> bf16 flat convert
__global__ __launch_bounds__(256) void f2b_kernel(
    const float* __restrict__ src, bf16* __restrict__ dst, int n)
{
    int i = blockIdx.x * 256 + threadIdx.x;
    if (i < n) dst[i] = __float2bfloat16(src[i]);
}

// ---------------------------------------------------------------------------
// Causal depthwise conv (K=4) + bias + silu, bf16 in, fp32 + bf16 out.
// ---------------------------------------------------------------------------
__global__ __launch_bounds__(256) void conv_silu_kernel(
    const bf16* __restrict__ xzb, const float* __restrict__ conv_w,
    const float* __restrict__ conv_b, float* __restrict__ xc,
    bf16* __restrict__ xcb)
{
    int idx = blockIdx.x * 256 + threadIdx.x;   // over M_*DI
    int d = idx & (DI - 1);
    int bt = idx >> 11;
    int t = bt & (T_ - 1);
    float acc = conv_b[d];
    #pragma unroll
    for (int k = 0; k < 4; ++k) {
        int tt = t + k - 3;
        if (tt >= 0)
            acc = fmaf(__bfloat162float(xzb[(size_t)(bt + (k - 3)) * 4096 + d]),
                       conv_w[d * 4 + k], acc);
    }
    float s = __fdividef(acc, 1.f + __expf(-acc));   // silu, native exp
    xc[idx] = s;
    xcb[idx] = __float2bfloat16(s);
}

// ---------------------------------------------------------------------------
// Selective scan. One thread per (b, d); h[16] in registers; sequential t.
// B/C rows for this b staged once into LDS (8 KB); per-t reads are
// same-address broadcasts (free). Native v_exp_f32 for the 16 state decays
// and the silu gate. Fuses + xc*D_skip and * silu(z). Writes y as bf16.
// ---------------------------------------------------------------------------
__global__ __launch_bounds__(256) void scan_kernel(
    const float* __restrict__ proj,   // (M_, 96): [64:80)=Bs, [80:96)=Cs
    const float* __restrict__ dtv,    // (M_, DI) softplus dt
    const float* __restrict__ xc,     // (M_, DI)
    const bf16*  __restrict__ xzb,    // (M_, 4096), z = cols [2048,4096)
    const float* __restrict__ A_log,  // (DI, 16)
    const float* __restrict__ D_skip, // (DI)
    bf16* __restrict__ yb)            // (M_, DI) out
{
    __shared__ float BC[64][32];      // [t][0:16)=B, [16:32)=C
    const int tid = threadIdx.x;
    const int b = blockIdx.y;         // 0..63
    for (int i = tid; i < 64 * 32; i += 256) {
        int t = i >> 5, c = i & 31;
        BC[t][c] = proj[(size_t)(b * 64 + t) * 96 + 64 + c];
    }
    __syncthreads();

    const int d = blockIdx.x * 256 + tid;    // 0..2047
    float A[16];
    #pragma unroll
    for (int n = 0; n < 16; ++n) A[n] = -__expf(A_log[d * 16 + n]);
    const float Dv = D_skip[d];
    float h[16];
    #pragma unroll
    for (int n = 0; n < 16; ++n) h[n] = 0.f;

    #pragma unroll 2
    for (int t = 0; t < T_; ++t) {
        int row = b * T_ + t;
        size_t off = (size_t)row * DI + d;
        float dt = dtv[off];
        float xv = xc[off];
        float dtx = dt * xv;
        float y = 0.f;
        #pragma unroll
        for (int n = 0; n < 16; ++n) {
            float dA = __expf(dt * A[n]);        // native v_exp_f32
            h[n] = fmaf(dA, h[n], dtx * BC[t][n]);
            y = fmaf(h[n], BC[t][16 + n], y);
        }
        float sk = fmaf(xv, Dv, y);
        float z = __bfloat162float(xzb[(size_t)row * 4096 + 2048 + d]);
        float g = __fdividef(z, 1.f + __expf(-z));   // silu(z)
        yb[off] = __float2bfloat16(sk * g);
    }
}

// ---------------------------------------------------------------------------
// Head: out[row, 0:6] = h2[row, :] @ W3 + b3.  One wave per row. h2 is bf16.
// ---------------------------------------------------------------------------
__global__ __launch_bounds__(256) void head_kernel(
    const bf16* __restrict__ h2, const float* __restrict__ W3,
    const float* __restrict__ b3, float* __restrict__ out)
{
    int row = blockIdx.x * 4 + (threadIdx.x >> 6);
    int lane = threadIdx.x & 63;
    const bf16* hr = h2 + (size_t)row * 256;
    float acc[6] = {0.f, 0.f, 0.f, 0.f, 0.f, 0.f};
    #pragma unroll
    for (int kk = 0; kk < 4; ++kk) {
        int k = lane + kk * 64;
        float hv = __bfloat162float(hr[k]);
        #pragma unroll
        for (int n = 0; n < 6; ++n) acc[n] = fmaf(hv, W3[k * 6 + n], acc[n]);
    }
    #pragma unroll
    for (int n = 0; n < 6; ++n) {
        float v = acc[n];
        #pragma unroll
        for (int off = 32; off > 0; off >>= 1) v += __shfl_down(v, off);
        if (lane == 0) out[(size_t)row * 6 + n] = v + b3[n];
    }
}

// ---------------------------------------------------------------------------
extern "C" void kernel_launch(void* const* d_in, const int* in_sizes, int n_in,
                              void* d_out, int out_size, void* d_ws, size_t ws_size,
                              hipStream_t stream)
{
    const float* spatial  = (const float*)d_in[0];
    const float* temporal = (const float*)d_in[1];
    const float* W_in     = (const float*)d_in[2];
    const float* conv_w   = (const float*)d_in[3];
    const float* conv_b   = (const float*)d_in[4];
    const float* W_x      = (const float*)d_in[5];
    const float* W_dt     = (const float*)d_in[6];
    const float* b_dt     = (const float*)d_in[7];
    const float* A_log    = (const float*)d_in[8];
    const float* D_skip   = (const float*)d_in[9];
    const float* W_out    = (const float*)d_in[10];
    const float* W1       = (const float*)d_in[11];
    const float* b1       = (const float*)d_in[12];
    const float* W2       = (const float*)d_in[13];
    const float* b2       = (const float*)d_in[14];
    const float* W3       = (const float*)d_in[15];
    const float* b3       = (const float*)d_in[16];
    float* out = (float*)d_out;

    // Workspace layout (bytes). Max footprint 135,790,592 B.
    char* w = (char*)d_ws;
    bf16*  xzb  = (bf16*)(w + 0);           // (M_,4096) bf16, 32 MiB; dead after scan
    bf16*  f    = (bf16*)(w + 0);           // (M_,1024) bf16, aliases xzb
    bf16*  h1   = (bf16*)(w + 8388608);     // (M_, 512) bf16
    bf16*  h2   = (bf16*)(w + 12582912);    // (M_, 256) bf16
    float* xc   = (float*)(w + 33554432);   // (M_,2048) fp32, 32 MiB; dead after scan
    bf16*  WoT  = (bf16*)(w + 33554432);    // (1024,2048) 4 MiB, written after scan
    bf16*  W1T  = (bf16*)(w + 37748736);    // (512,1024) 1 MiB
    bf16*  W2T  = (bf16*)(w + 38797312);    // (256,512) 256 KiB
    float* dtY  = (float*)(w + 67108864);   // (M_,2048) fp32, 32 MiB
    bf16*  WxT  = (bf16*)(w + 67108864);    // (96,2048) 384 KiB; dead before G3 writes dtY
    bf16*  xcb  = (bf16*)(w + 100663296);   // (M_,2048) bf16, 16 MiB; dead after G2
    bf16*  WdT  = (bf16*)(w + 100663296);   // (2048,64) 256 KiB, written after G2
    bf16*  yb   = (bf16*)(w + 100663296);   // (M_,2048) bf16, written by scan (WdT dead)
    bf16*  xb   = (bf16*)(w + 117440512);   // (M_,1024) bf16, 8 MiB; dead after G1
    bf16*  projb= (bf16*)(w + 117440512);   // (M_,96) bf16, aliases xb
    float* proj = (float*)(w + 125829120);  // (M_,96) fp32, 1.5 MiB
    bf16*  WinT = (bf16*)(w + 127401984);   // (4096,1024) 8 MiB; end 135790592

    dim3 blk(256);

    // Input conversions (+ zero proj for split-K accumulation)
    concat_kernel<<<dim3(4096), blk, 0, stream>>>(spatial, temporal, xb, proj);
    tconv_kernel<<<dim3(128, 32), blk, 0, stream>>>(W_in, WinT, 1024, 4096);

    // G1: xzb = xb @ W_in   (4096 x 4096, K=1024) -> bf16
    gemm_mfma<0, 1, 0><<<dim3(32, 32), blk, 0, stream>>>(
        xb, 1024, WinT, 1024, xzb, 4096, nullptr, 4096, 1024);

    // conv + silu -> xc (fp32) + xcb (bf16)
    conv_silu_kernel<<<dim3(32768), blk, 0, stream>>>(xzb, conv_w, conv_b, xc, xcb);

    // G2: proj += xc @ W_x   (4096 x 96, K=2048), split-K x4 for occupancy
    tconv_kernel<<<dim3(3, 64), blk, 0, stream>>>(W_x, WxT, 2048, 96);
    gemm_mfma<0, 0, 1><<<dim3(1, 32, 4), blk, 0, stream>>>(
        xcb, 2048, WxT, 2048, proj, 96, nullptr, 96, 2048);

    // G3: dt = softplus(proj[:, :64] @ W_dt + b_dt) -> fp32 dtY
    tconv_kernel<<<dim3(64, 2), blk, 0, stream>>>(W_dt, WdT, 64, 2048);
    f2b_kernel<<<dim3(1536), blk, 0, stream>>>(proj, projb, M_ * 96);
    gemm_mfma<2, 0, 0><<<dim3(16, 32), blk, 0, stream>>>(
        projb, 96, WdT, 64, dtY, 2048, b_dt, 2048, 64);

    // Selective scan + skip + gating -> yb (bf16)
    scan_kernel<<<dim3(8, 64), blk, 0, stream>>>(
        proj, dtY, xc, xzb, A_log, D_skip, yb);

    // Late weight transposes into now-dead xc region
    tconv_kernel<<<dim3(32, 64), blk, 0, stream>>>(W_out, WoT, 2048, 1024);
    tconv_kernel<<<dim3(16, 32), blk, 0, stream>>>(W1, W1T, 1024, 512);
    tconv_kernel<<<dim3(8, 16), blk, 0, stream>>>(W2, W2T, 512, 256);

    // G4: f = y @ W_out   (4096 x 1024, K=2048) -> bf16 (over dead xzb)
    gemm_mfma<0, 1, 0><<<dim3(8, 32), blk, 0, stream>>>(
        yb, 2048, WoT, 2048, f, 1024, nullptr, 1024, 2048);

    // G5: h1 = relu(f @ W1 + b1)   (4096 x 512, K=1024)
    gemm_mfma<1, 1, 0><<<dim3(4, 32), blk, 0, stream>>>(
        f, 1024, W1T, 1024, h1, 512, b1, 512, 1024);

    // G6: h2 = relu(h1 @ W2 + b2)   (4096 x 256, K=512)
    gemm_mfma<1, 1, 0><<<dim3(2, 32), blk, 0, stream>>>(
        h1, 512, W2T, 512, h2, 256, b2, 256, 512);

    // G7: out = h2 @ W3 + b3
    head_kernel<<<dim3(1024), blk, 0, stream>>>(h2, W3, b3, out);
}

// Round 4
// 393.397 us; speedup vs baseline: 4.1982x; 1.0352x over previous
//
#include <hip/hip_runtime.h>
#include <hip/hip_bf16.h>
#include <math.h>

// Problem constants
#define B_   64
#define T_   64
#define E_   512
#define DM   1024   // d_model
#define DI   2048   // d_inner
#define DS   16     // d_state
#define DTR  64     // dt_rank
#define M_   4096   // B*T rows

typedef __hip_bfloat16 bf16;
typedef __attribute__((ext_vector_type(8))) short bf16x8;   // 8 bf16 = 4 VGPRs
typedef __attribute__((ext_vector_type(4))) float f32x4;

__device__ __forceinline__ float b2f(short s) {
    return __uint_as_float(((unsigned)(unsigned short)s) << 16);
}

// ---------------------------------------------------------------------------
// bf16 MFMA GEMM: C[M x N] = act(A @ B + bias)
//   A  : bf16 (M x K) row-major, lda;  Bt : bf16 (N x K) row-major, ldb
// Block tile BM x BN (BK=32), 256 threads, 2x2 wave grid, (BM/32)x(BN/32)
// 16x16x32 MFMA tiles per wave. Staging via global_load_lds width=16 with
// XOR k-chunk swizzle (chunk' = chunk ^ (row&3)) to cut ds_read_b128 phase
// conflicts from 8-way to 4-way.
// ACT: 0 none, 1 relu, 2 softplus.
// SPLITK>1: gridDim.z-way K split, writes fp32 partials at z*M_*ldc (OUTBF=0).
// ---------------------------------------------------------------------------
template<int ACT, int OUTBF, int SPLITK, int BM, int BN>
__global__ __launch_bounds__(256) void gemm_mfma(
    const bf16* __restrict__ A, int lda,
    const bf16* __restrict__ Bt, int ldb,
    void* __restrict__ Cv, int ldc,
    const float* __restrict__ bias,
    int Ndim, int Kdim)
{
    __shared__ __align__(16) bf16 As[BM * 32];
    __shared__ __align__(16) bf16 Bs[BN * 32];
    const int tid  = threadIdx.x;
    const int wave = tid >> 6;
    const int lane = tid & 63;
    const int bm = blockIdx.y * BM;
    const int bn = blockIdx.x * BN;
    // staging: per issue, 64 lanes cover 16 rows x 4 k-chunks of 8 bf16 (16 B)
    const int lrow = lane >> 2;               // 0..15
    const int csw  = (lane & 3) ^ (lrow & 3); // swizzled k-chunk this lane loads
    constexpr int RPW = (BM + BN) / 4;        // rows staged per wave
    constexpr int NI  = RPW / 16;             // issues per wave
    // compute: 2x2 wave grid
    constexpr int WMT = BM / 32;              // 16-tiles per wave (M)
    constexpr int WNT = BN / 32;              // 16-tiles per wave (N)
    const int wm = (wave >> 1) * (BM / 2);
    const int wn = (wave & 1) * (BN / 2);
    const int fm = lane & 15;                 // fragment row/col
    const int fq = lane >> 4;                 // quad 0..3
    const int fsw = (fq ^ (fm & 3)) * 8;      // swizzled chunk offset for reads

    int kstart = 0, kend = Kdim;
    if (SPLITK > 1) {
        int chunk = Kdim / SPLITK;
        kstart = blockIdx.z * chunk;
        kend = kstart + chunk;
    }

    f32x4 acc[WMT][WNT];
    #pragma unroll
    for (int i = 0; i < WMT; ++i)
        #pragma unroll
        for (int j = 0; j < WNT; ++j)
            acc[i][j] = (f32x4){0.f, 0.f, 0.f, 0.f};

    for (int k0 = kstart; k0 < kend; k0 += 32) {
        #pragma unroll
        for (int i = 0; i < NI; ++i) {
            int rowbase = wave * RPW + i * 16;   // wave-uniform
            int row = rowbase + lrow;
            if (rowbase < BM) {
                const bf16* ga = A + (size_t)(bm + row) * lda + k0 + csw * 8;
                __builtin_amdgcn_global_load_lds(
                    (const __attribute__((address_space(1))) void*)ga,
                    (__attribute__((address_space(3))) void*)&As[rowbase * 32],
                    16, 0, 0);
            } else {
                int brow = bn + row - BM;
                if (brow >= Ndim) brow = Ndim - 1;   // clamp; cols>=Ndim unused
                const bf16* gb = Bt + (size_t)brow * ldb + k0 + csw * 8;
                __builtin_amdgcn_global_load_lds(
                    (const __attribute__((address_space(1))) void*)gb,
                    (__attribute__((address_space(3))) void*)&Bs[(rowbase - BM) * 32],
                    16, 0, 0);
            }
        }
        __syncthreads();
        bf16x8 a[WMT], b[WNT];
        #pragma unroll
        for (int i = 0; i < WMT; ++i)
            a[i] = *(const bf16x8*)&As[(wm + i * 16 + fm) * 32 + fsw];
        #pragma unroll
        for (int j = 0; j < WNT; ++j)
            b[j] = *(const bf16x8*)&Bs[(wn + j * 16 + fm) * 32 + fsw];
        #pragma unroll
        for (int i = 0; i < WMT; ++i)
            #pragma unroll
            for (int j = 0; j < WNT; ++j)
                acc[i][j] = __builtin_amdgcn_mfma_f32_16x16x32_bf16(
                    a[i], b[j], acc[i][j], 0, 0, 0);
        __syncthreads();
    }

    // Epilogue. C/D layout: col = lane&15, row = (lane>>4)*4 + r
    size_t zoff = (SPLITK > 1) ? (size_t)blockIdx.z * M_ * ldc : 0;
    #pragma unroll
    for (int i = 0; i < WMT; ++i) {
        int rowb = bm + wm + i * 16 + fq * 4;
        #pragma unroll
        for (int j = 0; j < WNT; ++j) {
            int col = bn + wn + j * 16 + fm;
            if (col < Ndim) {
                float bv = bias ? bias[col] : 0.f;
                #pragma unroll
                for (int r = 0; r < 4; ++r) {
                    float v = acc[i][j][r] + bv;
                    if (ACT == 1) v = fmaxf(v, 0.f);
                    if (ACT == 2) v = (v > 20.f) ? v : __logf(1.f + __expf(v));
                    size_t off = (size_t)(rowb + r) * ldc + col;
                    if (SPLITK > 1) ((float*)Cv)[zoff + off] = v;
                    else if (OUTBF) ((bf16*)Cv)[off] = __float2bfloat16(v);
                    else            ((float*)Cv)[off] = v;
                }
            }
        }
    }
}

// ---------------------------------------------------------------------------
// prep: one launch doing concat->bf16 (blocks [0,4096)) and all 5 weight
// transposes fp32(K,N) -> bf16(N,K) (32x32 LDS tiles, blocks [4096,11200)).
// ---------------------------------------------------------------------------
__global__ __launch_bounds__(256) void prep_kernel(
    const float* __restrict__ sp, const float* __restrict__ tp,
    bf16* __restrict__ xb,
    const float* __restrict__ W_in,  bf16* __restrict__ WinT,
    const float* __restrict__ W_x,   bf16* __restrict__ WxT,
    const float* __restrict__ W_dt,  bf16* __restrict__ WdT,
    const float* __restrict__ W_out, bf16* __restrict__ WoT,
    const float* __restrict__ W1,    bf16* __restrict__ W1T,
    const float* __restrict__ W2,    bf16* __restrict__ W2T)
{
    __shared__ float tile[32][33];
    const int b = blockIdx.x;
    const int tid = threadIdx.x;
    if (b < 4096) {
        // concat(spatial, temporal) -> xb (M_, 1024)
        int idx = b * 256 + tid;
        int row = idx >> 8;
        int c4 = (idx & 255) * 4;
        const float* src = (c4 < 512) ? (sp + (size_t)row * 512 + c4)
                                      : (tp + (size_t)row * 512 + (c4 - 512));
        float4 v = *(const float4*)src;
        bf16* dst = xb + (size_t)row * 1024 + c4;
        dst[0] = __float2bfloat16(v.x); dst[1] = __float2bfloat16(v.y);
        dst[2] = __float2bfloat16(v.z); dst[3] = __float2bfloat16(v.w);
        return;
    }
    const float* W; bf16* Wt; int K, N, tb;
    if      (b < 8192)  { W = W_in;  Wt = WinT; K = 1024; N = 4096; tb = b - 4096; }
    else if (b < 8384)  { W = W_x;   Wt = WxT;  K = 2048; N = 96;   tb = b - 8192; }
    else if (b < 8512)  { W = W_dt;  Wt = WdT;  K = 64;   N = 2048; tb = b - 8384; }
    else if (b < 10560) { W = W_out; Wt = WoT;  K = 2048; N = 1024; tb = b - 8512; }
    else if (b < 11072) { W = W1;    Wt = W1T;  K = 1024; N = 512;  tb = b - 10560; }
    else                { W = W2;    Wt = W2T;  K = 512;  N = 256;  tb = b - 11072; }
    int nb = N / 32;
    int bn = (tb % nb) * 32, bk = (tb / nb) * 32;
    int tx = tid & 31, ty = tid >> 5;
    #pragma unroll
    for (int i = 0; i < 32; i += 8)
        tile[ty + i][tx] = W[(size_t)(bk + ty + i) * N + bn + tx];
    __syncthreads();
    #pragma unroll
    for (int i = 0; i < 32; i += 8)
        Wt[(size_t)(bn + ty + i) * K + bk + tx] = __float2bfloat16(tile[tx][ty + i]);
}

// ---------------------------------------------------------------------------
// Causal depthwise conv (K=4) + bias + silu, bf16 in, bf16 out (for G2 only;
// the scan recomputes the fp32 conv inline). 4 channels per thread.
// ---------------------------------------------------------------------------
__global__ __launch_bounds__(256) void conv_silu_kernel(
    const bf16* __restrict__ xzb, const float* __restrict__ conv_w,
    const float* __restrict__ conv_b, bf16* __restrict__ xcb)
{
    int idx = blockIdx.x * 256 + threadIdx.x;   // over M_*DI/4
    int d4 = (idx & 511) * 4;                    // DI/4 = 512
    int bt = idx >> 9;
    int t = bt & (T_ - 1);
    float acc[4];
    #pragma unroll
    for (int j = 0; j < 4; ++j) acc[j] = conv_b[d4 + j];
    #pragma unroll
    for (int k = 0; k < 4; ++k) {
        int tt = t + k - 3;
        if (tt >= 0) {
            short4 xv4 = *(const short4*)&xzb[(size_t)(bt + k - 3) * 4096 + d4];
            acc[0] = fmaf(b2f(xv4.x), conv_w[(d4 + 0) * 4 + k], acc[0]);
            acc[1] = fmaf(b2f(xv4.y), conv_w[(d4 + 1) * 4 + k], acc[1]);
            acc[2] = fmaf(b2f(xv4.z), conv_w[(d4 + 2) * 4 + k], acc[2]);
            acc[3] = fmaf(b2f(xv4.w), conv_w[(d4 + 3) * 4 + k], acc[3]);
        }
    }
    bf16 o[4];
    #pragma unroll
    for (int j = 0; j < 4; ++j)
        o[j] = __float2bfloat16(__fdividef(acc[j], 1.f + __expf(-acc[j])));
    *(short4*)&xcb[(size_t)bt * DI + d4] = *(short4*)o;
}

// reduce 4 split-K partials -> proj fp32 + projb bf16
__global__ __launch_bounds__(256) void reduce4_kernel(
    const float* __restrict__ parts, float* __restrict__ proj,
    bf16* __restrict__ projb)
{
    int i = blockIdx.x * 256 + threadIdx.x;     // < 393216
    float s = parts[i] + parts[i + 393216] + parts[i + 786432] + parts[i + 1179648];
    proj[i] = s;
    projb[i] = __float2bfloat16(s);
}

// ---------------------------------------------------------------------------
// Selective scan. One thread per (b, d); h[16] in registers; sequential t.
// Recomputes the causal conv inline (3-reg rolling window over xzb) — same
// fp32 math as conv_silu, avoiding the 64 MB xc round-trip. B/C rows staged
// in LDS (broadcast reads). Fuses + xc*D_skip and * silu(z).
// ---------------------------------------------------------------------------
__global__ __launch_bounds__(256) void scan_kernel(
    const float* __restrict__ proj,   // (M_, 96): [64:80)=Bs, [80:96)=Cs
    const float* __restrict__ dtv,    // (M_, DI) softplus dt
    const bf16*  __restrict__ xzb,    // (M_, 4096): [0:2048)=xi, [2048:)=z
    const float* __restrict__ A_log,  // (DI, 16)
    const float* __restrict__ D_skip, // (DI)
    const float* __restrict__ conv_w, // (DI, 4)
    const float* __restrict__ conv_b, // (DI)
    bf16* __restrict__ yb)            // (M_, DI) out
{
    __shared__ float BC[64][32];      // [t][0:16)=B, [16:32)=C
    const int tid = threadIdx.x;
    const int b = blockIdx.y;         // 0..63
    for (int i = tid; i < 64 * 32; i += 256) {
        int t = i >> 5, c = i & 31;
        BC[t][c] = proj[(size_t)(b * 64 + t) * 96 + 64 + c];
    }
    __syncthreads();

    const int d = blockIdx.x * 256 + tid;    // 0..2047
    float A[16];
    #pragma unroll
    for (int n = 0; n < 16; ++n) A[n] = -__expf(A_log[d * 16 + n]);
    const float Dv = D_skip[d];
    const float cw0 = conv_w[d * 4 + 0], cw1 = conv_w[d * 4 + 1];
    const float cw2 = conv_w[d * 4 + 2], cw3 = conv_w[d * 4 + 3];
    const float cb = conv_b[d];
    float h[16];
    #pragma unroll
    for (int n = 0; n < 16; ++n) h[n] = 0.f;
    float w0 = 0.f, w1 = 0.f, w2 = 0.f;      // xzb[t-3], [t-2], [t-1]

    #pragma unroll 2
    for (int t = 0; t < T_; ++t) {
        int row = b * T_ + t;
        size_t off = (size_t)row * DI + d;
        float cur = __bfloat162float(xzb[(size_t)row * 4096 + d]);
        float cacc = cb;
        cacc = fmaf(w0, cw0, cacc); cacc = fmaf(w1, cw1, cacc);
        cacc = fmaf(w2, cw2, cacc); cacc = fmaf(cur, cw3, cacc);
        float xv = __fdividef(cacc, 1.f + __expf(-cacc));   // silu(conv)
        w0 = w1; w1 = w2; w2 = cur;

        float dt = dtv[off];
        float dtx = dt * xv;
        float y = 0.f;
        #pragma unroll
        for (int n = 0; n < 16; ++n) {
            float dA = __expf(dt * A[n]);
            h[n] = fmaf(dA, h[n], dtx * BC[t][n]);
            y = fmaf(h[n], BC[t][16 + n], y);
        }
        float sk = fmaf(xv, Dv, y);
        float z = __bfloat162float(xzb[(size_t)row * 4096 + 2048 + d]);
        float g = __fdividef(z, 1.f + __expf(-z));          // silu(z)
        yb[off] = __float2bfloat16(sk * g);
    }
}

// ---------------------------------------------------------------------------
// Head: out[row, 0:6] = h2[row, :] @ W3 + b3.  One wave per row. h2 is bf16.
// ---------------------------------------------------------------------------
__global__ __launch_bounds__(256) void head_kernel(
    const bf16* __restrict__ h2, const float* __restrict__ W3,
    const float* __restrict__ b3, float* __restrict__ out)
{
    int row = blockIdx.x * 4 + (threadIdx.x >> 6);
    int lane = threadIdx.x & 63;
    const bf16* hr = h2 + (size_t)row * 256;
    float acc[6] = {0.f, 0.f, 0.f, 0.f, 0.f, 0.f};
    #pragma unroll
    for (int kk = 0; kk < 4; ++kk) {
        int k = lane + kk * 64;
        float hv = __bfloat162float(hr[k]);
        #pragma unroll
        for (int n = 0; n < 6; ++n) acc[n] = fmaf(hv, W3[k * 6 + n], acc[n]);
    }
    #pragma unroll
    for (int n = 0; n < 6; ++n) {
        float v = acc[n];
        #pragma unroll
        for (int off = 32; off > 0; off >>= 1) v += __shfl_down(v, off);
        if (lane == 0) out[(size_t)row * 6 + n] = v + b3[n];
    }
}

// ---------------------------------------------------------------------------
extern "C" void kernel_launch(void* const* d_in, const int* in_sizes, int n_in,
                              void* d_out, int out_size, void* d_ws, size_t ws_size,
                              hipStream_t stream)
{
    const float* spatial  = (const float*)d_in[0];
    const float* temporal = (const float*)d_in[1];
    const float* W_in     = (const float*)d_in[2];
    const float* conv_w   = (const float*)d_in[3];
    const float* conv_b   = (const float*)d_in[4];
    const float* W_x      = (const float*)d_in[5];
    const float* W_dt     = (const float*)d_in[6];
    const float* b_dt     = (const float*)d_in[7];
    const float* A_log    = (const float*)d_in[8];
    const float* D_skip   = (const float*)d_in[9];
    const float* W_out    = (const float*)d_in[10];
    const float* W1       = (const float*)d_in[11];
    const float* b1       = (const float*)d_in[12];
    const float* W2       = (const float*)d_in[13];
    const float* b2       = (const float*)d_in[14];
    const float* W3       = (const float*)d_in[15];
    const float* b3       = (const float*)d_in[16];
    float* out = (float*)d_out;

    // Workspace layout (bytes), total 121,765,888 (< round-1's 135,790,592).
    char* w = (char*)d_ws;
    bf16*  xzb  = (bf16*)(w);                 // (M_,4096) 32 MiB; dead after scan
    bf16*  f    = (bf16*)(w);                 // (M_,1024) aliases xzb after scan
    bf16*  xcb  = (bf16*)(w + 33554432);      // (M_,2048) 16 MiB; dead after G2
    bf16*  yb   = (bf16*)(w + 33554432);      // (M_,2048) aliases xcb (scan out)
    float* dtv  = (float*)(w + 50331648);     // (M_,2048) fp32 32 MiB
    bf16*  xb   = (bf16*)(w + 83886080);      // (M_,1024) 8 MiB; dead after G1
    bf16*  WinT = (bf16*)(w + 92274688);      // (4096,1024) 8 MiB
    bf16*  WoT  = (bf16*)(w + 100663296);     // (1024,2048) 4 MiB
    bf16*  W1T  = (bf16*)(w + 104857600);     // (512,1024) 1 MiB
    bf16*  W2T  = (bf16*)(w + 105906176);     // (256,512) 256 KiB
    bf16*  WxT  = (bf16*)(w + 106168320);     // (96,2048) 384 KiB
    bf16*  WdT  = (bf16*)(w + 106561536);     // (2048,64) 256 KiB
    float* projp= (float*)(w + 106823680);    // 4x(M_,96) partials 6 MiB
    float* proj = (float*)(w + 113115136);    // (M_,96) fp32 1.5 MiB
    bf16*  projb= (bf16*)(w + 114688000);     // (M_,96) bf16 768 KiB
    bf16*  h1   = (bf16*)(w + 115474432);     // (M_,512) 4 MiB
    bf16*  h2   = (bf16*)(w + 119668736);     // (M_,256) 2 MiB

    dim3 blk(256);

    // 1. concat + all weight transposes
    prep_kernel<<<dim3(11200), blk, 0, stream>>>(
        spatial, temporal, xb, W_in, WinT, W_x, WxT, W_dt, WdT,
        W_out, WoT, W1, W1T, W2, W2T);

    // 2. G1: xzb = xb @ W_in   (4096 x 4096, K=1024)
    gemm_mfma<0, 1, 1, 128, 128><<<dim3(32, 32), blk, 0, stream>>>(
        xb, 1024, WinT, 1024, xzb, 4096, nullptr, 4096, 1024);

    // 3. conv + silu -> xcb (bf16, for G2)
    conv_silu_kernel<<<dim3(8192), blk, 0, stream>>>(xzb, conv_w, conv_b, xcb);

    // 4. G2: proj partials = xc @ W_x   (4096 x 96, K=2048), split-K x4
    gemm_mfma<0, 0, 4, 128, 128><<<dim3(1, 32, 4), blk, 0, stream>>>(
        xcb, 2048, WxT, 2048, projp, 96, nullptr, 96, 2048);

    // 5. reduce partials -> proj (fp32) + projb (bf16)
    reduce4_kernel<<<dim3(1536), blk, 0, stream>>>(projp, proj, projb);

    // 6. G3: dt = softplus(proj[:, :64] @ W_dt + b_dt)   (4096 x 2048, K=64)
    gemm_mfma<2, 0, 1, 128, 64><<<dim3(32, 32), blk, 0, stream>>>(
        projb, 96, WdT, 64, dtv, 2048, b_dt, 2048, 64);

    // 7. Selective scan (inline conv) + skip + gating -> yb
    scan_kernel<<<dim3(8, 64), blk, 0, stream>>>(
        proj, dtv, xzb, A_log, D_skip, conv_w, conv_b, yb);

    // 8. G4: f = y @ W_out   (4096 x 1024, K=2048), 512 blocks
    gemm_mfma<0, 1, 1, 128, 64><<<dim3(16, 32), blk, 0, stream>>>(
        yb, 2048, WoT, 2048, f, 1024, nullptr, 1024, 2048);

    // 9. G5: h1 = relu(f @ W1 + b1)   (4096 x 512, K=1024), 512 blocks
    gemm_mfma<1, 1, 1, 64, 64><<<dim3(8, 64), blk, 0, stream>>>(
        f, 1024, W1T, 1024, h1, 512, b1, 512, 1024);

    // 10. G6: h2 = relu(h1 @ W2 + b2)   (4096 x 256, K=512), 256 blocks
    gemm_mfma<1, 1, 1, 64, 64><<<dim3(4, 64), blk, 0, stream>>>(
        h1, 512, W2T, 512, h2, 256, b2, 256, 512);

    // 11. head
    head_kernel<<<dim3(1024), blk, 0, stream>>>(h2, W3, b3, out);
}